// Round 6
// baseline (210.945 us; speedup 1.0000x reference)
//
#include <hip/hip_runtime.h>

// NT-Xent: BATCH=4096, DIM=512, TEMP=0.5
// loss = mean_i [ log(sum_{j!=i} exp(2*cos(z_i,z_j))) - 2*cos(z_i, z_partner) ]
// R11: single-token fix of R10 — the residual spill was the register
// allocator's DEFAULT occupancy target. VGPR_Count=128 exactly (the 4-waves/EU
// budget step) with 380MB scratch traffic: acc alone needs 128 VGPRs, so the
// default cap spilled frags+addressing. __launch_bounds__(512, 2) declares
// 2 waves/EU -> 256-VGPR budget -> no spill (~200 live). R8's identical bound
// was innocent all along (the rule-#20 dynamic-index bug masked it).
// Geometry unchanged: 256x256 tile, 8 waves (2x4), 128x64/wave, BK=128,
// XOR-swizzled LDS chunks, single-buffer 64KB, atomic rowsum epilogue.

#define NROWS 8192
#define HALF_N 4096
#define KD 512              // elements per row (= 512 B/row in fp8)
#define BM 256              // block tile (square)
#define BK 128              // fp8 bytes of K per iter (8 chunks of 16 B per row)
#define NT2 (NROWS / BM)    // 32 block-tiles per side
#define NBLK (NT2 * (NT2 + 1) / 2)  // 528 (divisible by 8)

typedef unsigned char u8;
typedef __attribute__((ext_vector_type(4))) int i32x4;
typedef __attribute__((ext_vector_type(8))) int i32x8;
typedef __attribute__((ext_vector_type(4))) float f32x4;

__device__ inline void load16_to_lds(const u8* g, u8* l) {
  __builtin_amdgcn_global_load_lds((const __attribute__((address_space(1))) void*)g,
                                   (__attribute__((address_space(3))) void*)l,
                                   16, 0, 0);
}

// ---------------- normalize: z (fp32) -> zq (fp8 e4m3, unit rows) ------------
// wave-per-row: 4 rows/block, 2048 blocks. Also zeroes rowsum/possum/out.
__global__ __launch_bounds__(256) void nt_normalize(const float* __restrict__ zi,
                                                    const float* __restrict__ zj,
                                                    u8* __restrict__ zq,
                                                    float* __restrict__ rowsum,
                                                    float* __restrict__ possum,
                                                    float* __restrict__ out) {
  const int t = threadIdx.x;
  if (t < 4) rowsum[blockIdx.x * 4 + t] = 0.f;
  if (blockIdx.x == 0 && t == 4) { possum[0] = 0.f; out[0] = 0.f; }

  const int wave = t >> 6, lane = t & 63;
  const int row = blockIdx.x * 4 + wave;
  const float* src = (row < HALF_N) ? (zi + (size_t)row * KD)
                                    : (zj + (size_t)(row - HALF_N) * KD);
  const float4 v0 = ((const float4*)src)[lane * 2];
  const float4 v1 = ((const float4*)src)[lane * 2 + 1];
  float ss = v0.x * v0.x + v0.y * v0.y + v0.z * v0.z + v0.w * v0.w +
             v1.x * v1.x + v1.y * v1.y + v1.z * v1.z + v1.w * v1.w;
#pragma unroll
  for (int m = 1; m < 64; m <<= 1) ss += __shfl_xor(ss, m);
  const float inv = rsqrtf(ss);              // norms ~22.6, EPS irrelevant
  int lo = __builtin_amdgcn_cvt_pk_fp8_f32(v0.x * inv, v0.y * inv, 0, false);
  lo = __builtin_amdgcn_cvt_pk_fp8_f32(v0.z * inv, v0.w * inv, lo, true);
  int hi = __builtin_amdgcn_cvt_pk_fp8_f32(v1.x * inv, v1.y * inv, 0, false);
  hi = __builtin_amdgcn_cvt_pk_fp8_f32(v1.z * inv, v1.w * inv, hi, true);
  ((int2*)(zq + (size_t)row * KD))[lane] = make_int2(lo, hi);
}

// ---------------- GEMM + fused epilogue (upper-triangular 256^2 blocks) ------
// 8 waves in 2x4 grid, each wave owns a 128x64 output panel = 8x4 MFMA tiles
// of 16x16, one mfma_scale_f32_16x16x128 per tile-pair per K-iter (BK=128).
// LDS: 16B chunks at r*8 + (c ^ (r&7)) (XOR swizzle), A 32KB + B 32KB.
__global__ __launch_bounds__(512, 2) void nt_gemm(const u8* __restrict__ zq,
                                                  float* __restrict__ rowsum,
                                                  float* __restrict__ possum) {
  __shared__ __attribute__((aligned(16))) u8 lA[BM * BK];  // 32 KB
  __shared__ __attribute__((aligned(16))) u8 lB[BM * BK];  // 32 KB

  // XCD-chunked bijective swizzle (NBLK % 8 == 0).
  const int bid = (blockIdx.x & 7) * (NBLK / 8) + (blockIdx.x >> 3);

  // decode linear bid -> (tm, tn) with tn >= tm
  int tm = (int)((float)(2 * NT2 + 1) * 0.5f -
                 sqrtf((float)(2 * NT2 + 1) * (float)(2 * NT2 + 1) * 0.25f - 2.0f * (float)bid));
  if (tm < 0) tm = 0;
  if (tm > NT2 - 1) tm = NT2 - 1;
  while ((tm + 1) * NT2 - ((tm + 1) * tm) / 2 <= bid) ++tm;
  while (tm * NT2 - (tm * (tm - 1)) / 2 > bid) --tm;
  const int tn = tm + (bid - (tm * NT2 - (tm * (tm - 1)) / 2));
  const bool diag = (tm == tn);
  const bool isPos = (tn - tm == (HALF_N / BM));  // holds sim[i][i+N] diagonal

  const int t = threadIdx.x;
  const int wave = t >> 6, lane = t & 63;
  const int wm = wave >> 2, wn = wave & 3;        // 2 x 4 wave grid
  const int c16 = lane & 15, quad = lane >> 4;
  const int q2 = quad * 2;

  const int rowA = tm * BM, rowB = tn * BM;

  f32x4 acc[8][4] = {};

  const u8* Bt = diag ? lA : lB;   // diagonal blocks: B tile == A tile

  for (int k0 = 0; k0 < KD; k0 += BK) {
    __syncthreads();
    // stage 256x128 fp8 (= 2048 chunks of 16B) per tile; 4 chunks/thread
#pragma unroll
    for (int it = 0; it < 4; ++it) {
      const int chunk = it * 512 + t;           // destination chunk position
      const int r = chunk >> 3, cpos = chunk & 7;
      const int c = cpos ^ (r & 7);             // source column chunk (swizzle)
      u8* dstA = &lA[(it * 512 + wave * 64) * 16];  // wave-uniform
      load16_to_lds(&zq[(size_t)(rowA + r) * KD + k0 + c * 16], dstA);
      if (!diag) {
        u8* dstB = &lB[(it * 512 + wave * 64) * 16];
        load16_to_lds(&zq[(size_t)(rowB + r) * KD + k0 + c * 16], dstB);
      }
    }
    __syncthreads();   // compiler drains vmcnt before s_barrier

    i32x8 bg[4];
#pragma unroll
    for (int ni = 0; ni < 4; ++ni) {
      const int rB = wn * 64 + ni * 16 + c16;
      const i32x4 bl = *(const i32x4*)&Bt[(rB * 8 + (q2 ^ (rB & 7))) * 16];
      const i32x4 bh = *(const i32x4*)&Bt[(rB * 8 + ((q2 + 1) ^ (rB & 7))) * 16];
      bg[ni] = (i32x8){bl[0], bl[1], bl[2], bl[3], bh[0], bh[1], bh[2], bh[3]};
    }
    __builtin_amdgcn_s_setprio(1);
#pragma unroll
    for (int mi = 0; mi < 8; ++mi) {
      const int rA = wm * 128 + mi * 16 + c16;
      const i32x4 al = *(const i32x4*)&lA[(rA * 8 + (q2 ^ (rA & 7))) * 16];
      const i32x4 ah = *(const i32x4*)&lA[(rA * 8 + ((q2 + 1) ^ (rA & 7))) * 16];
      const i32x8 af = (i32x8){al[0], al[1], al[2], al[3], ah[0], ah[1], ah[2], ah[3]};
#pragma unroll
      for (int ni = 0; ni < 4; ++ni)
        acc[mi][ni] = __builtin_amdgcn_mfma_scale_f32_16x16x128_f8f6f4(
            af, bg[ni], acc[mi][ni],
            0, 0,                    // cbsz=fp8(e4m3), blgp=fp8(e4m3)
            0, 0x7F7F7F7F,           // scale A: opsel 0, E8M0 1.0
            0, 0x7F7F7F7F);          // scale B: opsel 0, E8M0 1.0
    }
    __builtin_amdgcn_s_setprio(0);
  }
  __syncthreads();   // all LDS frag reads done; lA reusable as scratch

  // lrow/lcol alias the dead A tile (saves static LDS to stay within 64 KB)
  float* lrow = (float*)lA;
  float* lcol = lrow + BM;

  // in-tile 16x16 diag tiles owned by waves with (wn>>1)==wm at mi=(wn&1)*4+ni.
  // RULE #20: never index acc[] with a runtime value — branch on wave-uniform
  // (wn&1) so all acc indices are compile-time; select on r==rdiag by VALUE.
  const bool ownDiag = (quad == (c16 >> 2));
  const int rdiag = c16 & 3;
  const bool diagWave = ((wn >> 1) == wm);
  const bool hiHalf = (wn & 1);

  // ---- positive pairs (pre-exp): sum 4*dot over this block's diagonal ----
  if (isPos && diagWave) {
    float p = 0.f;
    if (ownDiag) {
      if (!hiHalf) {
#pragma unroll
        for (int ni = 0; ni < 4; ++ni)
#pragma unroll
          for (int r = 0; r < 4; ++r)
            p += (r == rdiag) ? acc[ni][ni][r] : 0.f;
      } else {
#pragma unroll
        for (int ni = 0; ni < 4; ++ni)
#pragma unroll
          for (int r = 0; r < 4; ++r)
            p += (r == rdiag) ? acc[4 + ni][ni][r] : 0.f;
      }
    }
#pragma unroll
    for (int m = 1; m < 64; m <<= 1) p += __shfl_xor(p, m);
    if (lane == 0) atomicAdd(possum, 4.0f * p);
  }

  // ---- e = exp(2*sim) in place ----
#pragma unroll
  for (int mi = 0; mi < 8; ++mi)
#pragma unroll
    for (int ni = 0; ni < 4; ++ni)
#pragma unroll
      for (int r = 0; r < 4; ++r)
        acc[mi][ni][r] = __expf(2.0f * acc[mi][ni][r]);

  // ---- diagonal removal (diag blocks): zero exp(sim_ii) ----
  if (diag && diagWave && ownDiag) {
    if (!hiHalf) {
#pragma unroll
      for (int ni = 0; ni < 4; ++ni)
#pragma unroll
        for (int r = 0; r < 4; ++r)
          acc[ni][ni][r] = (r == rdiag) ? 0.f : acc[ni][ni][r];
    } else {
#pragma unroll
      for (int ni = 0; ni < 4; ++ni)
#pragma unroll
        for (int r = 0; r < 4; ++r)
          acc[4 + ni][ni][r] = (r == rdiag) ? 0.f : acc[4 + ni][ni][r];
    }
  }

  if (t < BM) { lrow[t] = 0.f; lcol[t] = 0.f; }
  __syncthreads();

  // row sums: reduce over ni (in-register) and c16 (shfl over lane bits 0-3)
#pragma unroll
  for (int mi = 0; mi < 8; ++mi) {
#pragma unroll
    for (int r = 0; r < 4; ++r) {
      float e = acc[mi][0][r] + acc[mi][1][r] + acc[mi][2][r] + acc[mi][3][r];
      e += __shfl_xor(e, 1);
      e += __shfl_xor(e, 2);
      e += __shfl_xor(e, 4);
      e += __shfl_xor(e, 8);
      if (c16 == 0) atomicAdd(&lrow[wm * 128 + mi * 16 + quad * 4 + r], e);
    }
  }
  // col sums: reduce over mi,r (in-register) and quad (shfl over lane bits 4-5)
  if (!diag) {
#pragma unroll
    for (int ni = 0; ni < 4; ++ni) {
      float g = 0.f;
#pragma unroll
      for (int mi = 0; mi < 8; ++mi)
#pragma unroll
        for (int r = 0; r < 4; ++r) g += acc[mi][ni][r];
      g += __shfl_xor(g, 16);
      g += __shfl_xor(g, 32);
      if (quad == 0) atomicAdd(&lcol[wn * 64 + ni * 16 + c16], g);
    }
  }
  __syncthreads();
  if (t < BM) {
    atomicAdd(&rowsum[rowA + t], lrow[t]);
    if (!diag) atomicAdd(&rowsum[rowB + t], lcol[t]);
  }
}

// ---------------- finalize: loss = (sum_i log(rowsum_i) - possum) / NROWS ----
__global__ __launch_bounds__(256) void nt_finalize(const float* __restrict__ rowsum,
                                                   const float* __restrict__ possum,
                                                   float* __restrict__ out) {
  const int t = threadIdx.x;
  const int i = blockIdx.x * 256 + t;
  float v = logf(rowsum[i]);
#pragma unroll
  for (int m = 1; m < 64; m <<= 1) v += __shfl_xor(v, m);
  __shared__ float bsum[4];
  if ((t & 63) == 0) bsum[t >> 6] = v;
  __syncthreads();
  if (t == 0) {
    float s = bsum[0] + bsum[1] + bsum[2] + bsum[3];
    if (blockIdx.x == 0) s -= possum[0];
    atomicAdd(out, s * (1.0f / NROWS));
  }
}

extern "C" void kernel_launch(void* const* d_in, const int* in_sizes, int n_in,
                              void* d_out, int out_size, void* d_ws, size_t ws_size,
                              hipStream_t stream) {
  const float* zi = (const float*)d_in[0];
  const float* zj = (const float*)d_in[1];
  float* out = (float*)d_out;

  // ws layout: zq (8192*512 fp8 = 4 MB) | rowsum (8192 f32) | possum (1 f32)
  u8* zq = (u8*)d_ws;
  float* rowsum = (float*)((char*)d_ws + (size_t)NROWS * KD);
  float* possum = rowsum + NROWS;

  nt_normalize<<<NROWS / 4, 256, 0, stream>>>(zi, zj, zq, rowsum, possum, out);
  nt_gemm<<<NBLK, 512, 0, stream>>>(zq, rowsum, possum);
  nt_finalize<<<NROWS / 256, 256, 0, stream>>>(rowsum, possum, out);
}

// Round 7
// 207.934 us; speedup vs baseline: 1.0145x; 1.0145x over previous
//
#include <hip/hip_runtime.h>

// NT-Xent: BATCH=4096, DIM=512, TEMP=0.5
// loss = mean_i [ log(sum_{j!=i} exp(2*cos(z_i,z_j))) - 2*cos(z_i, z_partner) ]
// R12: defeat the allocator's occupancy heuristic. Evidence R5/R10/R11: VGPR
// cap always lands at 512/(LDS-implied waves/EU); launch_bounds' min-waves arg
// is ignored. acc needs 128 VGPRs -> at cap 128 everything else spills
// (226MB scratch writes). Fix: (1) 20KB LDS pad -> 84KB total -> 1 block/CU
// -> LDS-implied 2 waves/EU -> cap 256; (2) amdgpu_waves_per_eu(2,2) pins the
// target explicitly. lrow/lcol live in the pad. No other changes: 256x256
// tile, 8 waves (2x4), 128x64/wave, BK=128, XOR-swizzled LDS, atomic rowsum.

#define NROWS 8192
#define HALF_N 4096
#define KD 512              // elements per row (= 512 B/row in fp8)
#define BM 256              // block tile (square)
#define BK 128              // fp8 bytes of K per iter (8 chunks of 16 B per row)
#define NT2 (NROWS / BM)    // 32 block-tiles per side
#define NBLK (NT2 * (NT2 + 1) / 2)  // 528 (divisible by 8)

typedef unsigned char u8;
typedef __attribute__((ext_vector_type(4))) int i32x4;
typedef __attribute__((ext_vector_type(8))) int i32x8;
typedef __attribute__((ext_vector_type(4))) float f32x4;

__device__ inline void load16_to_lds(const u8* g, u8* l) {
  __builtin_amdgcn_global_load_lds((const __attribute__((address_space(1))) void*)g,
                                   (__attribute__((address_space(3))) void*)l,
                                   16, 0, 0);
}

// ---------------- normalize: z (fp32) -> zq (fp8 e4m3, unit rows) ------------
// wave-per-row: 4 rows/block, 2048 blocks. Also zeroes rowsum/possum/out.
__global__ __launch_bounds__(256) void nt_normalize(const float* __restrict__ zi,
                                                    const float* __restrict__ zj,
                                                    u8* __restrict__ zq,
                                                    float* __restrict__ rowsum,
                                                    float* __restrict__ possum,
                                                    float* __restrict__ out) {
  const int t = threadIdx.x;
  if (t < 4) rowsum[blockIdx.x * 4 + t] = 0.f;
  if (blockIdx.x == 0 && t == 4) { possum[0] = 0.f; out[0] = 0.f; }

  const int wave = t >> 6, lane = t & 63;
  const int row = blockIdx.x * 4 + wave;
  const float* src = (row < HALF_N) ? (zi + (size_t)row * KD)
                                    : (zj + (size_t)(row - HALF_N) * KD);
  const float4 v0 = ((const float4*)src)[lane * 2];
  const float4 v1 = ((const float4*)src)[lane * 2 + 1];
  float ss = v0.x * v0.x + v0.y * v0.y + v0.z * v0.z + v0.w * v0.w +
             v1.x * v1.x + v1.y * v1.y + v1.z * v1.z + v1.w * v1.w;
#pragma unroll
  for (int m = 1; m < 64; m <<= 1) ss += __shfl_xor(ss, m);
  const float inv = rsqrtf(ss);              // norms ~22.6, EPS irrelevant
  int lo = __builtin_amdgcn_cvt_pk_fp8_f32(v0.x * inv, v0.y * inv, 0, false);
  lo = __builtin_amdgcn_cvt_pk_fp8_f32(v0.z * inv, v0.w * inv, lo, true);
  int hi = __builtin_amdgcn_cvt_pk_fp8_f32(v1.x * inv, v1.y * inv, 0, false);
  hi = __builtin_amdgcn_cvt_pk_fp8_f32(v1.z * inv, v1.w * inv, hi, true);
  ((int2*)(zq + (size_t)row * KD))[lane] = make_int2(lo, hi);
}

// ---------------- GEMM + fused epilogue (upper-triangular 256^2 blocks) ------
// 8 waves in 2x4 grid, each wave owns a 128x64 output panel = 8x4 MFMA tiles
// of 16x16, one mfma_scale_f32_16x16x128 per tile-pair per K-iter (BK=128).
// LDS: 16B chunks at r*8 + (c ^ (r&7)) (XOR swizzle), A 32KB + B 32KB + 20KB
// occupancy-shaping pad (-> 1 block/CU -> 2 waves/EU -> 256-VGPR budget).
__attribute__((amdgpu_waves_per_eu(2, 2)))
__global__ __launch_bounds__(512) void nt_gemm(const u8* __restrict__ zq,
                                               float* __restrict__ rowsum,
                                               float* __restrict__ possum) {
  __shared__ __attribute__((aligned(16))) u8 lA[BM * BK];      // 32 KB
  __shared__ __attribute__((aligned(16))) u8 lB[BM * BK];      // 32 KB
  __shared__ __attribute__((aligned(16))) u8 lpad[20 * 1024];  // 84 KB total

  float* lrow = (float*)lpad;        // 256 f32 (in the pad)
  float* lcol = lrow + BM;           // 256 f32

  // XCD-chunked bijective swizzle (NBLK % 8 == 0).
  const int bid = (blockIdx.x & 7) * (NBLK / 8) + (blockIdx.x >> 3);

  // decode linear bid -> (tm, tn) with tn >= tm
  int tm = (int)((float)(2 * NT2 + 1) * 0.5f -
                 sqrtf((float)(2 * NT2 + 1) * (float)(2 * NT2 + 1) * 0.25f - 2.0f * (float)bid));
  if (tm < 0) tm = 0;
  if (tm > NT2 - 1) tm = NT2 - 1;
  while ((tm + 1) * NT2 - ((tm + 1) * tm) / 2 <= bid) ++tm;
  while (tm * NT2 - (tm * (tm - 1)) / 2 > bid) --tm;
  const int tn = tm + (bid - (tm * NT2 - (tm * (tm - 1)) / 2));
  const bool diag = (tm == tn);
  const bool isPos = (tn - tm == (HALF_N / BM));  // holds sim[i][i+N] diagonal

  const int t = threadIdx.x;
  const int wave = t >> 6, lane = t & 63;
  const int wm = wave >> 2, wn = wave & 3;        // 2 x 4 wave grid
  const int c16 = lane & 15, quad = lane >> 4;
  const int q2 = quad * 2;

  const int rowA = tm * BM, rowB = tn * BM;

  f32x4 acc[8][4] = {};

  const u8* Bt = diag ? lA : lB;   // diagonal blocks: B tile == A tile

  for (int k0 = 0; k0 < KD; k0 += BK) {
    __syncthreads();
    // stage 256x128 fp8 (= 2048 chunks of 16B) per tile; 4 chunks/thread
#pragma unroll
    for (int it = 0; it < 4; ++it) {
      const int chunk = it * 512 + t;           // destination chunk position
      const int r = chunk >> 3, cpos = chunk & 7;
      const int c = cpos ^ (r & 7);             // source column chunk (swizzle)
      u8* dstA = &lA[(it * 512 + wave * 64) * 16];  // wave-uniform
      load16_to_lds(&zq[(size_t)(rowA + r) * KD + k0 + c * 16], dstA);
      if (!diag) {
        u8* dstB = &lB[(it * 512 + wave * 64) * 16];
        load16_to_lds(&zq[(size_t)(rowB + r) * KD + k0 + c * 16], dstB);
      }
    }
    __syncthreads();   // compiler drains vmcnt before s_barrier

    i32x8 bg[4];
#pragma unroll
    for (int ni = 0; ni < 4; ++ni) {
      const int rB = wn * 64 + ni * 16 + c16;
      const i32x4 bl = *(const i32x4*)&Bt[(rB * 8 + (q2 ^ (rB & 7))) * 16];
      const i32x4 bh = *(const i32x4*)&Bt[(rB * 8 + ((q2 + 1) ^ (rB & 7))) * 16];
      bg[ni] = (i32x8){bl[0], bl[1], bl[2], bl[3], bh[0], bh[1], bh[2], bh[3]};
    }
    __builtin_amdgcn_s_setprio(1);
#pragma unroll
    for (int mi = 0; mi < 8; ++mi) {
      const int rA = wm * 128 + mi * 16 + c16;
      const i32x4 al = *(const i32x4*)&lA[(rA * 8 + (q2 ^ (rA & 7))) * 16];
      const i32x4 ah = *(const i32x4*)&lA[(rA * 8 + ((q2 + 1) ^ (rA & 7))) * 16];
      const i32x8 af = (i32x8){al[0], al[1], al[2], al[3], ah[0], ah[1], ah[2], ah[3]};
#pragma unroll
      for (int ni = 0; ni < 4; ++ni)
        acc[mi][ni] = __builtin_amdgcn_mfma_scale_f32_16x16x128_f8f6f4(
            af, bg[ni], acc[mi][ni],
            0, 0,                    // cbsz=fp8(e4m3), blgp=fp8(e4m3)
            0, 0x7F7F7F7F,           // scale A: opsel 0, E8M0 1.0
            0, 0x7F7F7F7F);          // scale B: opsel 0, E8M0 1.0
    }
    __builtin_amdgcn_s_setprio(0);
  }

  // in-tile 16x16 diag tiles owned by waves with (wn>>1)==wm at mi=(wn&1)*4+ni.
  // RULE #20: never index acc[] with a runtime value — branch on wave-uniform
  // (wn&1) so all acc indices are compile-time; select on r==rdiag by VALUE.
  const bool ownDiag = (quad == (c16 >> 2));
  const int rdiag = c16 & 3;
  const bool diagWave = ((wn >> 1) == wm);
  const bool hiHalf = (wn & 1);

  // ---- positive pairs (pre-exp): sum 4*dot over this block's diagonal ----
  if (isPos && diagWave) {
    float p = 0.f;
    if (ownDiag) {
      if (!hiHalf) {
#pragma unroll
        for (int ni = 0; ni < 4; ++ni)
#pragma unroll
          for (int r = 0; r < 4; ++r)
            p += (r == rdiag) ? acc[ni][ni][r] : 0.f;
      } else {
#pragma unroll
        for (int ni = 0; ni < 4; ++ni)
#pragma unroll
          for (int r = 0; r < 4; ++r)
            p += (r == rdiag) ? acc[4 + ni][ni][r] : 0.f;
      }
    }
#pragma unroll
    for (int m = 1; m < 64; m <<= 1) p += __shfl_xor(p, m);
    if (lane == 0) atomicAdd(possum, 4.0f * p);
  }

  // ---- e = exp(2*sim) in place ----
#pragma unroll
  for (int mi = 0; mi < 8; ++mi)
#pragma unroll
    for (int ni = 0; ni < 4; ++ni)
#pragma unroll
      for (int r = 0; r < 4; ++r)
        acc[mi][ni][r] = __expf(2.0f * acc[mi][ni][r]);

  // ---- diagonal removal (diag blocks): zero exp(sim_ii) ----
  if (diag && diagWave && ownDiag) {
    if (!hiHalf) {
#pragma unroll
      for (int ni = 0; ni < 4; ++ni)
#pragma unroll
        for (int r = 0; r < 4; ++r)
          acc[ni][ni][r] = (r == rdiag) ? 0.f : acc[ni][ni][r];
    } else {
#pragma unroll
      for (int ni = 0; ni < 4; ++ni)
#pragma unroll
        for (int r = 0; r < 4; ++r)
          acc[4 + ni][ni][r] = (r == rdiag) ? 0.f : acc[4 + ni][ni][r];
    }
  }

  if (t < BM) { lrow[t] = 0.f; lcol[t] = 0.f; }
  __syncthreads();

  // row sums: reduce over ni (in-register) and c16 (shfl over lane bits 0-3)
#pragma unroll
  for (int mi = 0; mi < 8; ++mi) {
#pragma unroll
    for (int r = 0; r < 4; ++r) {
      float e = acc[mi][0][r] + acc[mi][1][r] + acc[mi][2][r] + acc[mi][3][r];
      e += __shfl_xor(e, 1);
      e += __shfl_xor(e, 2);
      e += __shfl_xor(e, 4);
      e += __shfl_xor(e, 8);
      if (c16 == 0) atomicAdd(&lrow[wm * 128 + mi * 16 + quad * 4 + r], e);
    }
  }
  // col sums: reduce over mi,r (in-register) and quad (shfl over lane bits 4-5)
  if (!diag) {
#pragma unroll
    for (int ni = 0; ni < 4; ++ni) {
      float g = 0.f;
#pragma unroll
      for (int mi = 0; mi < 8; ++mi)
#pragma unroll
        for (int r = 0; r < 4; ++r) g += acc[mi][ni][r];
      g += __shfl_xor(g, 16);
      g += __shfl_xor(g, 32);
      if (quad == 0) atomicAdd(&lcol[wn * 64 + ni * 16 + c16], g);
    }
  }
  __syncthreads();
  if (t < BM) {
    atomicAdd(&rowsum[rowA + t], lrow[t]);
    if (!diag) atomicAdd(&rowsum[rowB + t], lcol[t]);
  }
}

// ---------------- finalize: loss = (sum_i log(rowsum_i) - possum) / NROWS ----
__global__ __launch_bounds__(256) void nt_finalize(const float* __restrict__ rowsum,
                                                   const float* __restrict__ possum,
                                                   float* __restrict__ out) {
  const int t = threadIdx.x;
  const int i = blockIdx.x * 256 + t;
  float v = logf(rowsum[i]);
#pragma unroll
  for (int m = 1; m < 64; m <<= 1) v += __shfl_xor(v, m);
  __shared__ float bsum[4];
  if ((t & 63) == 0) bsum[t >> 6] = v;
  __syncthreads();
  if (t == 0) {
    float s = bsum[0] + bsum[1] + bsum[2] + bsum[3];
    if (blockIdx.x == 0) s -= possum[0];
    atomicAdd(out, s * (1.0f / NROWS));
  }
}

extern "C" void kernel_launch(void* const* d_in, const int* in_sizes, int n_in,
                              void* d_out, int out_size, void* d_ws, size_t ws_size,
                              hipStream_t stream) {
  const float* zi = (const float*)d_in[0];
  const float* zj = (const float*)d_in[1];
  float* out = (float*)d_out;

  // ws layout: zq (8192*512 fp8 = 4 MB) | rowsum (8192 f32) | possum (1 f32)
  u8* zq = (u8*)d_ws;
  float* rowsum = (float*)((char*)d_ws + (size_t)NROWS * KD);
  float* possum = rowsum + NROWS;

  nt_normalize<<<NROWS / 4, 256, 0, stream>>>(zi, zj, zq, rowsum, possum, out);
  nt_gemm<<<NBLK, 512, 0, stream>>>(zq, rowsum, possum);
  nt_finalize<<<NROWS / 256, 256, 0, stream>>>(rowsum, possum, out);
}

// Round 8
// 143.463 us; speedup vs baseline: 1.4704x; 1.4494x over previous
//
#include <hip/hip_runtime.h>

// NT-Xent: BATCH=4096, DIM=512, TEMP=0.5
// loss = mean_i [ log(sum_{j!=i} exp(2*cos(z_i,z_j))) - 2*cos(z_i, z_partner) ]
// R13: LDS-free K-loop. The 256^2 arc died on a hard 128-VGPR allocator cap
// (R8-R12). Back to the proven 128^2 / 4-wave / acc[4][4] shape (116 VGPR,
// no spill) but with the one thing R5-R7 never varied removed: the LDS
// round-trip. zq (4MB) is L2-resident; MFMA A/B fragments are loaded DIRECTLY
// from global (lane pattern: 16 rows x 128B contiguous per wave -> 64B lines
// fully used, 4 lanes/line). Deletes staging, all K-loop barriers (waves run
// free until the epilogue), all bank conflicts, and the diag special case.
// Floor: ~532MB from L2 (~21us) overlapped with ~7.5us MFMA at 16 waves/CU.

#define NROWS 8192
#define HALF_N 4096
#define KD 512            // elements per row (= 512 B/row in fp8)
#define TILE 128
#define BK 128            // fp8 bytes of K per MFMA (one 16x16x128 per pair)
#define NT (NROWS / TILE) // 64 block-tiles per side
#define NBLK (NT * (NT + 1) / 2)  // 2080 (divisible by 8)

typedef unsigned char u8;
typedef __attribute__((ext_vector_type(4))) int i32x4;
typedef __attribute__((ext_vector_type(8))) int i32x8;
typedef __attribute__((ext_vector_type(4))) float f32x4;

// ---------------- normalize: z (fp32) -> zq (fp8 e4m3, unit rows) ------------
// wave-per-row: 4 rows/block, 2048 blocks. Also zeroes rowsum/possum/out.
__global__ __launch_bounds__(256) void nt_normalize(const float* __restrict__ zi,
                                                    const float* __restrict__ zj,
                                                    u8* __restrict__ zq,
                                                    float* __restrict__ rowsum,
                                                    float* __restrict__ possum,
                                                    float* __restrict__ out) {
  const int t = threadIdx.x;
  if (t < 4) rowsum[blockIdx.x * 4 + t] = 0.f;
  if (blockIdx.x == 0 && t == 4) { possum[0] = 0.f; out[0] = 0.f; }

  const int wave = t >> 6, lane = t & 63;
  const int row = blockIdx.x * 4 + wave;
  const float* src = (row < HALF_N) ? (zi + (size_t)row * KD)
                                    : (zj + (size_t)(row - HALF_N) * KD);
  const float4 v0 = ((const float4*)src)[lane * 2];
  const float4 v1 = ((const float4*)src)[lane * 2 + 1];
  float ss = v0.x * v0.x + v0.y * v0.y + v0.z * v0.z + v0.w * v0.w +
             v1.x * v1.x + v1.y * v1.y + v1.z * v1.z + v1.w * v1.w;
#pragma unroll
  for (int m = 1; m < 64; m <<= 1) ss += __shfl_xor(ss, m);
  const float inv = rsqrtf(ss);              // norms ~22.6, EPS irrelevant
  int lo = __builtin_amdgcn_cvt_pk_fp8_f32(v0.x * inv, v0.y * inv, 0, false);
  lo = __builtin_amdgcn_cvt_pk_fp8_f32(v0.z * inv, v0.w * inv, lo, true);
  int hi = __builtin_amdgcn_cvt_pk_fp8_f32(v1.x * inv, v1.y * inv, 0, false);
  hi = __builtin_amdgcn_cvt_pk_fp8_f32(v1.z * inv, v1.w * inv, hi, true);
  ((int2*)(zq + (size_t)row * KD))[lane] = make_int2(lo, hi);
}

// ---------------- GEMM + fused epilogue (upper-triangular blocks) ----------
// 128x128 tile per block, 4 waves in 2x2, each wave 4x4 MFMA tiles of 16x16.
// Fragments loaded straight from global (L2-hot zq): lane(c16,quad) reads
// row (base + sub*16 + c16), bytes k0 + quad*32 .. +32. No LDS in the K-loop.
__global__ __launch_bounds__(256) void nt_gemm(const u8* __restrict__ zq,
                                               float* __restrict__ rowsum,
                                               float* __restrict__ possum) {
  __shared__ float lrow[TILE];
  __shared__ float lcol[TILE];

  // XCD-chunked bijective swizzle (NBLK % 8 == 0): same-tm blocks share an XCD.
  const int bid = (blockIdx.x & 7) * (NBLK / 8) + (blockIdx.x >> 3);

  // decode linear bid -> (tm, tn) with tn >= tm
  int tm = (int)((float)(2 * NT + 1) * 0.5f -
                 sqrtf((float)(2 * NT + 1) * (float)(2 * NT + 1) * 0.25f - 2.0f * (float)bid));
  if (tm < 0) tm = 0;
  if (tm > NT - 1) tm = NT - 1;
  while ((tm + 1) * NT - ((tm + 1) * tm) / 2 <= bid) ++tm;
  while (tm * NT - (tm * (tm - 1)) / 2 > bid) --tm;
  const int tn = tm + (bid - (tm * NT - (tm * (tm - 1)) / 2));
  const bool diag = (tm == tn);
  const bool isPos = (tn - tm == 32);   // block diagonal holds sim[i][i+N]

  const int t = threadIdx.x;
  const int wave = t >> 6, lane = t & 63;
  const int wm = wave >> 1, wn = wave & 1;
  const int c16 = lane & 15, quad = lane >> 4;

  // per-lane base pointers: row = (tile base + sub*16 + c16), col byte = quad*32
  const u8* baseA = zq + (size_t)(tm * TILE + wm * 64 + c16) * KD + quad * 32;
  const u8* baseB = zq + (size_t)(tn * TILE + wn * 64 + c16) * KD + quad * 32;

  f32x4 acc[4][4] = {};

  for (int k0 = 0; k0 < KD; k0 += BK) {
    i32x8 bg[4];
#pragma unroll
    for (int ni = 0; ni < 4; ++ni) {
      const u8* pb = baseB + (size_t)(ni * 16) * KD + k0;
      const i32x4 bl = *(const i32x4*)pb;
      const i32x4 bh = *(const i32x4*)(pb + 16);
      bg[ni] = (i32x8){bl[0], bl[1], bl[2], bl[3], bh[0], bh[1], bh[2], bh[3]};
    }
#pragma unroll
    for (int mi = 0; mi < 4; ++mi) {
      const u8* pa = baseA + (size_t)(mi * 16) * KD + k0;
      const i32x4 al = *(const i32x4*)pa;
      const i32x4 ah = *(const i32x4*)(pa + 16);
      const i32x8 af = (i32x8){al[0], al[1], al[2], al[3], ah[0], ah[1], ah[2], ah[3]};
#pragma unroll
      for (int ni = 0; ni < 4; ++ni)
        acc[mi][ni] = __builtin_amdgcn_mfma_scale_f32_16x16x128_f8f6f4(
            af, bg[ni], acc[mi][ni],
            0, 0,                    // cbsz=fp8(e4m3), blgp=fp8(e4m3)
            0, 0x7F7F7F7F,           // scale A: opsel 0, E8M0 1.0
            0, 0x7F7F7F7F);          // scale B: opsel 0, E8M0 1.0
    }
  }

  // in-tile diagonal ownership: row(quad*4+r) == col(c16) <=> quad==c16>>2, r==c16&3
  const bool ownDiag = (quad == (c16 >> 2));
  const int rdiag = c16 & 3;

  // ---- positive pairs (pre-exp): sum 4*dot over this block's diagonal ----
  if (isPos && wm == wn) {
    float p = 0.f;
    if (ownDiag) {
#pragma unroll
      for (int mi = 0; mi < 4; ++mi)
#pragma unroll
        for (int r = 0; r < 4; ++r)
          p += (r == rdiag) ? acc[mi][mi][r] : 0.f;
    }
#pragma unroll
    for (int m = 1; m < 64; m <<= 1) p += __shfl_xor(p, m);
    if (lane == 0) atomicAdd(possum, 4.0f * p);
  }

  // ---- e = exp(2*sim) in place ----
#pragma unroll
  for (int mi = 0; mi < 4; ++mi)
#pragma unroll
    for (int ni = 0; ni < 4; ++ni)
#pragma unroll
      for (int r = 0; r < 4; ++r)
        acc[mi][ni][r] = __expf(2.0f * acc[mi][ni][r]);

  // ---- diagonal removal (diag blocks): zero exp(sim_ii) ----
  if (diag && wm == wn && ownDiag) {
#pragma unroll
    for (int mi = 0; mi < 4; ++mi)
#pragma unroll
      for (int r = 0; r < 4; ++r)
        acc[mi][mi][r] = (r == rdiag) ? 0.f : acc[mi][mi][r];
  }

  if (t < TILE) { lrow[t] = 0.f; lcol[t] = 0.f; }
  __syncthreads();

  // row sums: reduce over ni (in-register) and c16 (shfl over lane bits 0-3)
#pragma unroll
  for (int mi = 0; mi < 4; ++mi) {
#pragma unroll
    for (int r = 0; r < 4; ++r) {
      float e = acc[mi][0][r] + acc[mi][1][r] + acc[mi][2][r] + acc[mi][3][r];
      e += __shfl_xor(e, 1);
      e += __shfl_xor(e, 2);
      e += __shfl_xor(e, 4);
      e += __shfl_xor(e, 8);
      if (c16 == 0) atomicAdd(&lrow[wm * 64 + mi * 16 + quad * 4 + r], e);
    }
  }
  // col sums: reduce over mi,r (in-register) and quad (shfl over lane bits 4-5)
  if (!diag) {
#pragma unroll
    for (int ni = 0; ni < 4; ++ni) {
      float g = 0.f;
#pragma unroll
      for (int mi = 0; mi < 4; ++mi)
#pragma unroll
        for (int r = 0; r < 4; ++r) g += acc[mi][ni][r];
      g += __shfl_xor(g, 16);
      g += __shfl_xor(g, 32);
      if (quad == 0) atomicAdd(&lcol[wn * 64 + ni * 16 + c16], g);
    }
  }
  __syncthreads();
  if (t < TILE) {
    atomicAdd(&rowsum[tm * TILE + t], lrow[t]);
    if (!diag) atomicAdd(&rowsum[tn * TILE + t], lcol[t]);
  }
}

// ---------------- finalize: loss = (sum_i log(rowsum_i) - possum) / NROWS ----
__global__ __launch_bounds__(256) void nt_finalize(const float* __restrict__ rowsum,
                                                   const float* __restrict__ possum,
                                                   float* __restrict__ out) {
  const int t = threadIdx.x;
  const int i = blockIdx.x * 256 + t;
  float v = logf(rowsum[i]);
#pragma unroll
  for (int m = 1; m < 64; m <<= 1) v += __shfl_xor(v, m);
  __shared__ float bsum[4];
  if ((t & 63) == 0) bsum[t >> 6] = v;
  __syncthreads();
  if (t == 0) {
    float s = bsum[0] + bsum[1] + bsum[2] + bsum[3];
    if (blockIdx.x == 0) s -= possum[0];
    atomicAdd(out, s * (1.0f / NROWS));
  }
}

extern "C" void kernel_launch(void* const* d_in, const int* in_sizes, int n_in,
                              void* d_out, int out_size, void* d_ws, size_t ws_size,
                              hipStream_t stream) {
  const float* zi = (const float*)d_in[0];
  const float* zj = (const float*)d_in[1];
  float* out = (float*)d_out;

  // ws layout: zq (8192*512 fp8 = 4 MB) | rowsum (8192 f32) | possum (1 f32)
  u8* zq = (u8*)d_ws;
  float* rowsum = (float*)((char*)d_ws + (size_t)NROWS * KD);
  float* possum = rowsum + NROWS;

  nt_normalize<<<NROWS / 4, 256, 0, stream>>>(zi, zj, zq, rowsum, possum, out);
  nt_gemm<<<NBLK, 256, 0, stream>>>(zq, rowsum, possum);
  nt_finalize<<<NROWS / 256, 256, 0, stream>>>(rowsum, possum, out);
}